// Round 7
// baseline (163.968 us; speedup 1.0000x reference)
//
#include <hip/hip_runtime.h>
#include <stdint.h>

#define N_PROP 100000
#define N_LAB  256
#define NW     8                      // 256 bits / 32
#define CHUNK  256
#define NCHUNK 391                    // ceil(100000/256)
#define NCH_P  392                    // padded stride for transposed chunkOR
#define N_PAD  (NCHUNK * CHUNK)       // 100096

// d_ws byte offsets
#define OFF_MASKS   0
#define OFF_CHUNKOR (N_PAD * NW * 4)                   // 3,203,072
#define OFF_TPCNT   (OFF_CHUNKOR + NCHUNK * NW * 4)
#define OFF_KEYS    (OFF_TPCNT + 16)                   // 256 x u64
#define OFF_HIST    (OFF_KEYS + N_LAB * 8)             // 257 x int

// first pending label from 4 x u64 pending words (-1 if none)
#define FIRST_PEND(j_i, w0, w1, w2, w3)         \
  {                                             \
    j_i = -1;                                   \
    if (w3) j_i = 192 + (__ffsll(w3) - 1);      \
    if (w2) j_i = 128 + (__ffsll(w2) - 1);      \
    if (w1) j_i = 64 + (__ffsll(w1) - 1);       \
    if (w0) j_i = (__ffsll(w0) - 1);            \
  }

// ---------------------------------------------------------------------------
// Kernel 1 (unchanged, proven): per-proposal 256-bit IoU>0.5 masks +
// per-chunk OR. Block 0 zeroes the global histogram. Arithmetic bit-identical
// to the reference (IEEE div, same op order).
// ---------------------------------------------------------------------------
__global__ __launch_bounds__(256) void k_masks(
    const float* __restrict__ prop, const float* __restrict__ lab,
    uint32_t* __restrict__ masks, uint32_t* __restrict__ chunkOR,
    int* __restrict__ hist) {
  __shared__ float4 s_lab[N_LAB];     // (bmin, bmax, blen, 0)
  __shared__ uint32_t s_or[NW];
  const int t = threadIdx.x;
  if (t < NW) s_or[t] = 0u;
  {
    const float bmn = lab[2 * t], bmx = lab[2 * t + 1];
    s_lab[t] = make_float4(bmn, bmx, bmx - bmn, 0.0f);
  }
  if (blockIdx.x == 0) {
    hist[t] = 0;
    if (t == 0) hist[N_LAB] = 0;
  }
  __syncthreads();

  const int i = blockIdx.x * 256 + t;
  uint32_t m[NW];
#pragma unroll
  for (int w = 0; w < NW; ++w) m[w] = 0u;

  if (i < N_PROP) {
    const float ps = prop[3 * i + 1], pe = prop[3 * i + 2];
    const float amin = ps / 25.0f;
    const float amax = pe / 25.0f;
    const float alen = amax - amin;
#pragma unroll 4
    for (int j = 0; j < N_LAB; ++j) {
      const float4 L = s_lab[j];
      float inter = fminf(amax, L.y) - fmaxf(amin, L.x);
      inter = fmaxf(inter, 0.0f);
      const float uni = (alen - inter) + L.z;
      const float iou = inter / uni;           // IEEE div, as reference
      if (iou > 0.5f) m[j >> 5] |= (1u << (j & 31));
    }
  }

  uint4* mp = reinterpret_cast<uint4*>(&masks[(size_t)i * NW]);
  mp[0] = make_uint4(m[0], m[1], m[2], m[3]);
  mp[1] = make_uint4(m[4], m[5], m[6], m[7]);

  uint32_t any = 0u;
#pragma unroll
  for (int w = 0; w < NW; ++w) any |= m[w];
  if (any) {
#pragma unroll
    for (int w = 0; w < NW; ++w)
      if (m[w]) atomicOr(&s_or[w], m[w]);
  }
  __syncthreads();
  if (t < NW) chunkOR[blockIdx.x * NW + t] = s_or[t];
}

// ---------------------------------------------------------------------------
// Kernel 2: exact sequential greedy scan (wave 0) + TP key sort (all 256).
// Claim semantics proven vs reference (R4/R6, absmax 0.0): proposals
// evaluated exactly once in ascending index order; a proposal claims the
// first label of (mask & ~detected), if any, then stops. detected only
// grows => chunk-OR prefilter is sound AND forward-only scanning is exact
// (chunks <= cur are fully consumed even if their OR still intersects ~D).
//
// Perf vs R6 (67 us): (a) chunkOR staged TRANSPOSED in LDS -> sweeps cost
// LDS latency, conflict-free; (b) next flagged chunk found under pre-drain D
// (superset test) and its masks prefetched into named registers WHILE the
// current chunk drains, then re-validated under the grown D (alias-free;
// cur strictly increases -> terminates in <= NCHUNK iterations).
// ---------------------------------------------------------------------------
#define FLAG_LANE(CC, FVAR)                                                 \
  FVAR = (s_orT[0 * NCH_P + (CC)] & ~D0) | (s_orT[1 * NCH_P + (CC)] & ~D1) |\
         (s_orT[2 * NCH_P + (CC)] & ~D2) | (s_orT[3 * NCH_P + (CC)] & ~D3) |\
         (s_orT[4 * NCH_P + (CC)] & ~D4) | (s_orT[5 * NCH_P + (CC)] & ~D5) |\
         (s_orT[6 * NCH_P + (CC)] & ~D6) | (s_orT[7 * NCH_P + (CC)] & ~D7);

#define FIND_NEXT(C0, RES)                                                  \
  {                                                                         \
    const int start_ = (C0);            /* evaluate BEFORE touching RES */  \
    RES = -1;                                                               \
    for (int c_ = start_; c_ < NCHUNK; c_ += 64) {                          \
      const int cc_ = c_ + lane;                                            \
      uint32_t f_ = 0u;                                                     \
      if (cc_ < NCHUNK) { FLAG_LANE(cc_, f_); }                             \
      const unsigned long long bal_ = __ballot(f_ != 0u);                   \
      if (bal_ != 0ull) { RES = c_ + (__ffsll(bal_) - 1); break; }          \
    }                                                                       \
  }

// masks has N_PAD rows (all written by k_masks); CH <= 390 -> max uint4
// index = 390*512 + 511 = 200,191 < N_PAD*NW/4 = 200,192: always in-bounds.
#define ISSUE(CH, R0A, R0B, R1A, R1B, R2A, R2B, R3A, R3B)                   \
  {                                                                         \
    const uint4* qm_ =                                                      \
        reinterpret_cast<const uint4*>(&masks[(size_t)(CH) * CHUNK * NW]);  \
    const int l2_ = lane * 2;                                               \
    R0A = qm_[l2_];       R0B = qm_[l2_ + 1];                               \
    R1A = qm_[128 + l2_]; R1B = qm_[128 + l2_ + 1];                         \
    R2A = qm_[256 + l2_]; R2B = qm_[256 + l2_ + 1];                         \
    R3A = qm_[384 + l2_]; R3B = qm_[384 + l2_ + 1];                         \
  }

#define DRAIN_ROW(BASE, VA, VB)                                             \
  {                                                                         \
    unsigned long long w0 = ((unsigned long long)(VA.y & ~D1) << 32) |      \
                            (unsigned long long)(uint32_t)(VA.x & ~D0);     \
    unsigned long long w1 = ((unsigned long long)(VA.w & ~D3) << 32) |      \
                            (unsigned long long)(uint32_t)(VA.z & ~D2);     \
    unsigned long long w2 = ((unsigned long long)(VB.y & ~D5) << 32) |      \
                            (unsigned long long)(uint32_t)(VB.x & ~D4);     \
    unsigned long long w3 = ((unsigned long long)(VB.w & ~D7) << 32) |      \
                            (unsigned long long)(uint32_t)(VB.z & ~D6);     \
    int j_i;                                                                \
    FIRST_PEND(j_i, w0, w1, w2, w3);                                        \
    unsigned long long rbal = __ballot(j_i >= 0);                           \
    while (rbal != 0ull) {                                                  \
      const int l_ = __ffsll(rbal) - 1;                                     \
      rbal &= rbal - 1;                                                     \
      const int j_ = __builtin_amdgcn_readlane(j_i, l_);                    \
      if (j_ >= 0) {                                                        \
        const uint32_t bit_ = 1u << (j_ & 31);                              \
        const int q5_ = j_ >> 5;                                            \
        D0 |= (q5_ == 0) ? bit_ : 0u;  D1 |= (q5_ == 1) ? bit_ : 0u;        \
        D2 |= (q5_ == 2) ? bit_ : 0u;  D3 |= (q5_ == 3) ? bit_ : 0u;        \
        D4 |= (q5_ == 4) ? bit_ : 0u;  D5 |= (q5_ == 5) ? bit_ : 0u;        \
        D6 |= (q5_ == 6) ? bit_ : 0u;  D7 |= (q5_ == 7) ? bit_ : 0u;        \
        const unsigned long long bm_ = 1ull << (j_ & 63);                   \
        const int q6_ = j_ >> 6;                                            \
        w0 &= (q6_ == 0) ? ~bm_ : ~0ull;  w1 &= (q6_ == 1) ? ~bm_ : ~0ull;  \
        w2 &= (q6_ == 2) ? ~bm_ : ~0ull;  w3 &= (q6_ == 3) ? ~bm_ : ~0ull;  \
        FIRST_PEND(j_i, w0, w1, w2, w3);                                    \
        if (lane == 0 && T < N_LAB) s_tpi[T] = (BASE) + l_;                 \
        ++T;                                                                \
      }                                                                     \
    }                                                                       \
  }

#define COPY_BA                                                             \
  a0A = b0A; a0B = b0B; a1A = b1A; a1B = b1B;                               \
  a2A = b2A; a2B = b2B; a3A = b3A; a3B = b3B;

__global__ __launch_bounds__(256) void k_scansort(
    const uint32_t* __restrict__ masks, const uint32_t* __restrict__ chunkOR,
    const float* __restrict__ prop,
    unsigned long long* __restrict__ keys, int* __restrict__ tp_cnt) {
  __shared__ uint32_t s_orT[NW * NCH_P];       // transposed: [word][chunk]
  __shared__ int s_tpi[N_LAB];
  __shared__ int s_T;
  __shared__ unsigned long long s_key[N_LAB];
  __shared__ unsigned long long s_srt[N_LAB];
  const int t = threadIdx.x;

  // stage chunkOR transposed (f = c*8+w -> s_orT[w][c]); coalesced reads,
  // 2-way-max LDS write aliasing (free). Lane-consecutive sweep reads are
  // then bank-conflict-free.
  for (int f = t; f < NCHUNK * NW; f += 256)
    s_orT[(f & 7) * NCH_P + (f >> 3)] = chunkOR[f];
  __syncthreads();

  if (t < 64) {
    const int lane = t;
    uint32_t D0 = 0, D1 = 0, D2 = 0, D3 = 0, D4 = 0, D5 = 0, D6 = 0, D7 = 0;
    int T = 0;
    uint4 a0A, a0B, a1A, a1B, a2A, a2B, a3A, a3B;   // current chunk masks
    uint4 b0A, b0B, b1A, b1B, b2A, b2B, b3A, b3B;   // prefetched next chunk

    int cur;
    FIND_NEXT(0, cur);
    if (cur >= 0) { ISSUE(cur, a0A, a0B, a1A, a1B, a2A, a2B, a3A, a3B); }
    while (cur >= 0) {
      int nxt;
      FIND_NEXT(cur + 1, nxt);                 // superset test (pre-drain D)
      if (nxt >= 0) { ISSUE(nxt, b0A, b0B, b1A, b1B, b2A, b2B, b3A, b3B); }

      DRAIN_ROW(cur * CHUNK + 0,   a0A, a0B);
      DRAIN_ROW(cur * CHUNK + 64,  a1A, a1B);
      DRAIN_ROW(cur * CHUNK + 128, a2A, a2B);
      DRAIN_ROW(cur * CHUNK + 192, a3A, a3B);

      // re-validate nxt under the grown D (flags only shrink)
      while (nxt >= 0) {
        uint32_t fu;
        FLAG_LANE(nxt, fu);                    // uniform addr -> broadcast
        if (fu != 0u) break;
        FIND_NEXT(nxt + 1, nxt);
        if (nxt >= 0) { ISSUE(nxt, b0A, b0B, b1A, b1B, b2A, b2B, b3A, b3B); }
      }
      cur = nxt;                               // strictly increases
      if (cur >= 0) { COPY_BA }
    }
    if (lane == 0) s_T = T;
  }
  __syncthreads();

  // ---- TP key build + counting sort (all 256 threads; proven in R4/R6) ----
  // key = conf_bits<<32 | (0xFFFFFFFF - idx): exactly the reference's stable
  // argsort(-conf) priority (conf >= 0; ties -> lower idx first).
  int T = s_T;
  T = (T < 0) ? 0 : ((T > N_LAB) ? N_LAB : T);
  unsigned long long k = ~0ull;
  if (t < T) {
    const int it = s_tpi[t];
    const unsigned cb = __float_as_uint(prop[3 * it]);
    k = ((unsigned long long)cb << 32) |
        (unsigned long long)(0xFFFFFFFFu - (unsigned)it);
  }
  s_key[t] = k;
  s_srt[t] = ~0ull;
  __syncthreads();
  int pos = 0;
  for (int s = 0; s < N_LAB; ++s) pos += (s_key[s] < k) ? 1 : 0;
  if (t < T) s_srt[pos] = k;                   // real keys distinct
  __syncthreads();
  keys[t] = s_srt[t];
  if (t == 0) tp_cnt[0] = T;
}

// ---------------------------------------------------------------------------
// Kernel 3 (unchanged, proven): rank histogram. p_i = #{sorted TP keys <
// key_i} via exact lower_bound in [0,256] (9-step guarded search).
// ---------------------------------------------------------------------------
__global__ __launch_bounds__(256) void k_rank(
    const float* __restrict__ prop, const unsigned long long* __restrict__ keys,
    int* __restrict__ hist) {
  __shared__ unsigned long long s_key[N_LAB];
  __shared__ int s_hist[N_LAB + 1];
  const int t = threadIdx.x;
  s_key[t] = keys[t];
  s_hist[t] = 0;
  if (t == 0) s_hist[N_LAB] = 0;
  __syncthreads();

  const int i = blockIdx.x * 256 + t;
  if (i < N_PROP) {
    const unsigned cb = __float_as_uint(prop[3 * i]);
    const unsigned long long k =
        ((unsigned long long)cb << 32) |
        (unsigned long long)(0xFFFFFFFFu - (unsigned)i);
    int p = 0;
#pragma unroll
    for (int s = 256; s > 0; s >>= 1) {
      const int cand = p + s;
      if (cand <= N_LAB && s_key[cand - 1] < k) p = cand;
    }
    atomicAdd(&s_hist[p], 1);
  }
  __syncthreads();
  if (s_hist[t] != 0) atomicAdd(&hist[t], s_hist[t]);
  if (t == 0 && s_hist[N_LAB] != 0) atomicAdd(&hist[N_LAB], s_hist[N_LAB]);
}

// ---------------------------------------------------------------------------
// Kernel 4 (unchanged, proven): exact integer suffix-sum of hist, ranks in
// priority order, then the bit-exact fp AP loop.
// AP = (1/256) * sum_{i: p_i >= 2} max_{j>=i} (j / p_j); rank-1 term
// excluded (reference's x[:-1] quirk).
// ---------------------------------------------------------------------------
__global__ __launch_bounds__(256) void k_ap(
    const int* __restrict__ tp_cnt, const int* __restrict__ hist,
    float* __restrict__ out) {
  __shared__ int s_a[N_LAB + 1];
  __shared__ int s_b[N_LAB + 1];
  __shared__ int s_p[N_LAB];
  const int t = threadIdx.x;
  int T = tp_cnt[0];
  T = (T < 0) ? 0 : ((T > N_LAB) ? N_LAB : T);
  s_a[t] = hist[t];
  if (t == 0) s_a[N_LAB] = hist[N_LAB];
  __syncthreads();
  int* src = s_a;
  int* dst = s_b;
#pragma unroll
  for (int s = 1; s <= N_LAB; s <<= 1) {
    const int v = src[t] + ((t + s <= N_LAB) ? src[t + s] : 0);
    const int v256 = (t == 0) ? src[N_LAB] : 0;
    __syncthreads();
    dst[t] = v;
    if (t == 0) dst[N_LAB] = v256;
    __syncthreads();
    int* tmp = src; src = dst; dst = tmp;
  }
  if (t < T) s_p[(T - 1) - t] = 1 + src[t + 1];
  __syncthreads();
  if (t == 0) {
    float m = 0.0f, sum = 0.0f;
    for (int i = T - 1; i >= 0; --i) {
      const float prec = (float)(i + 1) / (float)s_p[i];  // IEEE div, as ref
      m = fmaxf(m, prec);
      if (s_p[i] >= 2) sum += m * 0.00390625f;  // * (1/256), exact
    }
    out[0] = sum;
  }
}

extern "C" void kernel_launch(void* const* d_in, const int* in_sizes, int n_in,
                              void* d_out, int out_size, void* d_ws,
                              size_t ws_size, hipStream_t stream) {
  (void)in_sizes; (void)n_in; (void)out_size; (void)ws_size;
  const float* prop = (const float*)d_in[0];
  const float* lab  = (const float*)d_in[1];
  uint8_t* ws = (uint8_t*)d_ws;
  uint32_t* masks  = (uint32_t*)(ws + OFF_MASKS);
  uint32_t* chOR   = (uint32_t*)(ws + OFF_CHUNKOR);
  int*      tp_cnt = (int*)(ws + OFF_TPCNT);
  unsigned long long* keys = (unsigned long long*)(ws + OFF_KEYS);
  int*      hist   = (int*)(ws + OFF_HIST);
  float*    out    = (float*)d_out;

  k_masks   <<<dim3(NCHUNK), dim3(256), 0, stream>>>(prop, lab, masks, chOR, hist);
  k_scansort<<<dim3(1),      dim3(256), 0, stream>>>(masks, chOR, prop, keys, tp_cnt);
  k_rank    <<<dim3(NCHUNK), dim3(256), 0, stream>>>(prop, keys, hist);
  k_ap      <<<dim3(1),      dim3(256), 0, stream>>>(tp_cnt, hist, out);
}